// Round 23
// baseline (543.145 us; speedup 1.0000x reference)
//
#include <hip/hip_runtime.h>
#include <math.h>

#define NN 30000
#define PP 8
#define DM 128
#define EE 1000
#define NNZC 120000
#define DIN (PP*DM)   // 1024

typedef __attribute__((ext_vector_type(8))) short bf16x8;
typedef __attribute__((ext_vector_type(4))) float f32x4;

__device__ __forceinline__ short f2bf(float f) {
    union { float f; unsigned u; } v; v.f = f;
    unsigned r = v.u + 0x7fffu + ((v.u >> 16) & 1u);
    return (short)(r >> 16);
}
__device__ __forceinline__ float bf2f(short s) {
    union { unsigned u; float f; } v;
    v.u = ((unsigned)(unsigned short)s) << 16;
    return v.f;
}

// ---------------------------------------------------------------- CSR build
__global__ void count_kernel(const int* __restrict__ ei, const int* __restrict__ ni,
                             int* __restrict__ ecnt, int* __restrict__ ncnt) {
    int k = blockIdx.x * 256 + threadIdx.x;
    if (k >= NNZC) return;
    atomicAdd(&ecnt[ei[k]], 1);
    atomicAdd(&ncnt[ni[k]], 1);
}

__global__ __launch_bounds__(1024)
void scan_two(const int* __restrict__ ecnt, int* __restrict__ eoff,
              const int* __restrict__ ncnt, int* __restrict__ noff) {
    const int* cnt; int* off; int len;
    if (blockIdx.x == 0) { cnt = ecnt; off = eoff; len = EE; }
    else                 { cnt = ncnt; off = noff; len = NN; }
    __shared__ int wsum[16];
    __shared__ int carrysh;
    int t = threadIdx.x;
    int lane = t & 63, w = t >> 6;
    if (t == 0) carrysh = 0;
    __syncthreads();
    for (int base = 0; base < len; base += 1024) {
        int v = (base + t < len) ? cnt[base + t] : 0;
        int s = v;
        #pragma unroll
        for (int d = 1; d < 64; d <<= 1) {
            int u = __shfl_up(s, d);
            if (lane >= d) s += u;
        }
        if (lane == 63) wsum[w] = s;
        __syncthreads();
        if (t < 16) {
            int ws = wsum[t];
            #pragma unroll
            for (int d = 1; d < 16; d <<= 1) {
                int u = __shfl_up(ws, d);
                if (t >= d) ws += u;
            }
            wsum[t] = ws;
        }
        __syncthreads();
        int c = carrysh;
        int woff = (w > 0) ? wsum[w - 1] : 0;
        if (base + t < len) off[base + t] = c + woff + s - v;
        int total = wsum[15];
        __syncthreads();
        if (t == 0) carrysh = c + total;
    }
    __syncthreads();
    if (t == 0) off[len] = carrysh;
}

__global__ void fill_lists(const int* __restrict__ ei, const int* __restrict__ ni,
                           const int* __restrict__ eoff, const int* __restrict__ noff,
                           int* __restrict__ ecur, int* __restrict__ ncur,
                           int* __restrict__ elist, int* __restrict__ nlist) {
    int k = blockIdx.x * 256 + threadIdx.x;
    if (k >= NNZC) return;
    int e = ei[k];
    int p = atomicAdd(&ecur[e], 1);
    elist[eoff[e] + p] = k;
    int n = ni[k];
    int q = atomicAdd(&ncur[n], 1);
    nlist[noff[n] + q] = k;
}

// ---------------------------------------------------------------- weight transpose+convert
__global__ void transpose_to_bf16(const float* __restrict__ B, short* __restrict__ BT,
                                  int K, int N) {
    __shared__ float tile[32][33];
    int bn = blockIdx.x * 32, bk = blockIdx.y * 32;
    int tx = threadIdx.x & 31, ty = threadIdx.x >> 5;
    #pragma unroll
    for (int yy = ty; yy < 32; yy += 8) {
        int k = bk + yy, n = bn + tx;
        tile[yy][tx] = (k < K && n < N) ? B[(size_t)k * N + n] : 0.f;
    }
    __syncthreads();
    #pragma unroll
    for (int yy = ty; yy < 32; yy += 8) {
        int n = bn + yy, k = bk + tx;
        if (n < N && k < K) BT[(size_t)n * K + k] = f2bf(tile[tx][yy]);
    }
}

// ---------------------------------------------------------------- GEMM1 split-K=4 (bf16 partials)
__global__ __launch_bounds__(256)
void gemm1_splitk(const float* __restrict__ x, const short* __restrict__ W1T,
                  short* __restrict__ hp) {
    __shared__ short As[64 * 40];
    __shared__ short Bs[128 * 40];
    const int tid = threadIdx.x;
    const int lane = tid & 63, wid = tid >> 6;
    const int wm = wid >> 1, wn = wid & 1;
    const int panel = blockIdx.x >> 2, kq = blockIdx.x & 3;
    const int row0 = panel * 64;
    const int kbase = kq * 256;
    const int srow = tid >> 2, skq = tid & 3;

    f32x4 acc[2][4] = {};
    struct Stage { float4 fa[2]; bf16x8 b[2]; };
    Stage s0, s1;

    auto loadT = [&](int t, Stage& s) {
        int k0 = kbase + (t << 5);
        int gr = row0 + srow;
        float4 z = make_float4(0.f, 0.f, 0.f, 0.f);
        s.fa[0] = z; s.fa[1] = z;
        if (gr < NN) {
            const float4* p = (const float4*)(x + (size_t)gr * DIN + k0 + skq * 8);
            s.fa[0] = p[0]; s.fa[1] = p[1];
        }
        #pragma unroll
        for (int c = 0; c < 2; ++c)
            s.b[c] = *(const bf16x8*)(W1T + (size_t)(srow + 64 * c) * DIN + k0 + skq * 8);
    };
    auto writeT = [&](Stage& s) {
        bf16x8 t8;
        t8[0] = f2bf(s.fa[0].x); t8[1] = f2bf(s.fa[0].y);
        t8[2] = f2bf(s.fa[0].z); t8[3] = f2bf(s.fa[0].w);
        t8[4] = f2bf(s.fa[1].x); t8[5] = f2bf(s.fa[1].y);
        t8[6] = f2bf(s.fa[1].z); t8[7] = f2bf(s.fa[1].w);
        *(bf16x8*)&As[srow * 40 + skq * 8] = t8;
        #pragma unroll
        for (int c = 0; c < 2; ++c)
            *(bf16x8*)&Bs[(srow + 64 * c) * 40 + skq * 8] = s.b[c];
    };
    auto compute = [&]() {
        bf16x8 av[2], bv[4];
        #pragma unroll
        for (int i = 0; i < 2; ++i)
            av[i] = *(const bf16x8*)&As[(wm * 32 + i * 16 + (lane & 15)) * 40 + (lane >> 4) * 8];
        #pragma unroll
        for (int j = 0; j < 4; ++j)
            bv[j] = *(const bf16x8*)&Bs[(wn * 64 + j * 16 + (lane & 15)) * 40 + (lane >> 4) * 8];
        #pragma unroll
        for (int i = 0; i < 2; ++i)
            #pragma unroll
            for (int j = 0; j < 4; ++j)
                acc[i][j] = __builtin_amdgcn_mfma_f32_16x16x32_bf16(av[i], bv[j], acc[i][j], 0, 0, 0);
    };

    loadT(0, s0);
    for (int t = 0; t < 8; t += 2) {
        __syncthreads();
        loadT(t + 1, s1);
        writeT(s0);
        __syncthreads();
        compute();
        __syncthreads();
        if (t + 2 < 8) loadT(t + 2, s0);
        writeT(s1);
        __syncthreads();
        compute();
    }

    short* o = hp + (size_t)kq * NN * 128;
    #pragma unroll
    for (int i = 0; i < 2; ++i) {
        #pragma unroll
        for (int q = 0; q < 4; ++q) {
            int row = row0 + wm * 32 + i * 16 + (lane >> 4) * 4 + q;
            if (row < NN) {
                #pragma unroll
                for (int j = 0; j < 4; ++j) {
                    int col = wn * 64 + j * 16 + (lane & 15);
                    o[(size_t)row * 128 + col] = f2bf(acc[i][j][q]);
                }
            }
        }
    }
}

// ---------------------------------------------------------------- combine: h = leaky(sum hp(bf16) + b1), BN1 stats
__global__ void combine_bn1(const short* __restrict__ hp, const float* __restrict__ b1,
                            float* __restrict__ h, float* __restrict__ spart) {
    int t = threadIdx.x;
    const short4* p0 = (const short4*)hp;
    const short4* p1 = (const short4*)(hp + (size_t)NN * 128);
    const short4* p2 = (const short4*)(hp + (size_t)2 * NN * 128);
    const short4* p3 = (const short4*)(hp + (size_t)3 * NN * 128);
    float4* o = (float4*)h;
    int c = (t & 31) * 4;
    float4 bb = *(const float4*)(b1 + c);
    long long idx = (long long)blockIdx.x * 256 + t;
    long long stride = (long long)gridDim.x * 256;
    float s1[4] = {0.f,0.f,0.f,0.f}, s2[4] = {0.f,0.f,0.f,0.f};
    for (; idx < (long long)NN * 32; idx += stride) {
        short4 a = p0[idx], b = p1[idx], cc = p2[idx], dd = p3[idx];
        float v0 = bf2f(a.x) + bf2f(b.x) + bf2f(cc.x) + bf2f(dd.x) + bb.x;
        float v1 = bf2f(a.y) + bf2f(b.y) + bf2f(cc.y) + bf2f(dd.y) + bb.y;
        float v2 = bf2f(a.z) + bf2f(b.z) + bf2f(cc.z) + bf2f(dd.z) + bb.z;
        float v3 = bf2f(a.w) + bf2f(b.w) + bf2f(cc.w) + bf2f(dd.w) + bb.w;
        v0 = v0 > 0.f ? v0 : 0.2f * v0;
        v1 = v1 > 0.f ? v1 : 0.2f * v1;
        v2 = v2 > 0.f ? v2 : 0.2f * v2;
        v3 = v3 > 0.f ? v3 : 0.2f * v3;
        o[idx] = make_float4(v0, v1, v2, v3);
        s1[0] += v0; s2[0] += v0 * v0;
        s1[1] += v1; s2[1] += v1 * v1;
        s1[2] += v2; s2[2] += v2 * v2;
        s1[3] += v3; s2[3] += v3 * v3;
    }
    __shared__ float r1[256][4], r2[256][4];
    #pragma unroll
    for (int k = 0; k < 4; ++k) { r1[t][k] = s1[k]; r2[t][k] = s2[k]; }
    __syncthreads();
    if (t < 32) {
        #pragma unroll
        for (int k = 0; k < 4; ++k) {
            float a1 = 0.f, a2 = 0.f;
            #pragma unroll
            for (int u = 0; u < 8; ++u) { a1 += r1[t + u * 32][k]; a2 += r2[t + u * 32][k]; }
            spart[(size_t)blockIdx.x * 256 + t * 4 + k] = a1;
            spart[(size_t)blockIdx.x * 256 + 128 + t * 4 + k] = a2;
        }
    }
}

// ---------------------------------------------------------------- W2 GEMM: 128x128 tile, 8 waves (2x4)
__global__ __launch_bounds__(512)
void gemm_w2(const short* __restrict__ hb, const short* __restrict__ W2T,
             const float* __restrict__ bias, const float* __restrict__ srcf,
             short* __restrict__ outb, float* __restrict__ spart) {
    __shared__ short As[128 * 40];
    __shared__ short Bs[128 * 40];
    const int tid = threadIdx.x;
    const int lane = tid & 63, wid = tid >> 6;
    const int wm = wid >> 2, wn = wid & 3;        // 2 x 4 wave grid
    int row0, col0;
    {
        int w = blockIdx.x;
        int cpx = gridDim.x >> 3;
        int l = (w & 7) * cpx + (w >> 3);
        row0 = (l / 8) * 128;
        col0 = (l % 8) * 128;
    }
    const int sr = tid >> 2, kq = tid & 3;

    f32x4 acc[4][2] = {};
    struct Stage { bf16x8 a, b; };
    Stage s0, s1;

    auto loadT = [&](int t, Stage& s) {
        int k0 = t << 5;
        int gr = row0 + sr;
        s.a = bf16x8{0, 0, 0, 0, 0, 0, 0, 0};
        if (gr < NN) s.a = *(const bf16x8*)(hb + (size_t)gr * 128 + k0 + kq * 8);
        s.b = *(const bf16x8*)(W2T + (size_t)(col0 + sr) * 128 + k0 + kq * 8);
    };
    auto writeT = [&](Stage& s) {
        *(bf16x8*)&As[sr * 40 + kq * 8] = s.a;
        *(bf16x8*)&Bs[sr * 40 + kq * 8] = s.b;
    };
    auto compute = [&]() {
        bf16x8 av[4], bv[2];
        #pragma unroll
        for (int i = 0; i < 4; ++i)
            av[i] = *(const bf16x8*)&As[(wm * 64 + i * 16 + (lane & 15)) * 40 + (lane >> 4) * 8];
        #pragma unroll
        for (int j = 0; j < 2; ++j)
            bv[j] = *(const bf16x8*)&Bs[(wn * 32 + j * 16 + (lane & 15)) * 40 + (lane >> 4) * 8];
        #pragma unroll
        for (int i = 0; i < 4; ++i)
            #pragma unroll
            for (int j = 0; j < 2; ++j)
                acc[i][j] = __builtin_amdgcn_mfma_f32_16x16x32_bf16(av[i], bv[j], acc[i][j], 0, 0, 0);
    };

    loadT(0, s0);
    for (int t = 0; t < 4; t += 2) {
        __syncthreads();
        loadT(t + 1, s1);
        writeT(s0);
        __syncthreads();
        compute();
        __syncthreads();
        if (t + 2 < 4) loadT(t + 2, s0);
        writeT(s1);
        __syncthreads();
        compute();
    }

    float lsum[2] = {0.f, 0.f}, lsq[2] = {0.f, 0.f};
    #pragma unroll
    for (int i = 0; i < 4; ++i) {
        #pragma unroll
        for (int q = 0; q < 4; ++q) {
            int row = row0 + wm * 64 + i * 16 + (lane >> 4) * 4 + q;
            if (row < NN) {
                #pragma unroll
                for (int j = 0; j < 2; ++j) {
                    int col = col0 + wn * 32 + j * 16 + (lane & 15);
                    float val = acc[i][j][q];
                    val += bias[col];
                    val = val > 0.f ? val : 0.2f * val;
                    val += srcf[(size_t)row * DIN + col];
                    lsum[j] += val; lsq[j] += val * val;
                    outb[(size_t)row * DIN + col] = f2bf(val);
                }
            }
        }
    }
    __syncthreads();
    float* sred = (float*)As;
    if (tid < 256) sred[tid] = 0.f;
    __syncthreads();
    int chb = wn * 32 + (lane & 15);
    #pragma unroll
    for (int j = 0; j < 2; ++j) {
        atomicAdd(&sred[chb + j * 16], lsum[j]);
        atomicAdd(&sred[128 + chb + j * 16], lsq[j]);
    }
    __syncthreads();
    if (tid < 256) spart[(size_t)blockIdx.x * 256 + tid] = sred[tid];
}

// ---------------------------------------------------------------- fold per-block partials into accum[256]
__global__ void reduce_stats(const float* __restrict__ part, int nblk, float* __restrict__ accum) {
    int t = threadIdx.x;
    float s = 0.f;
    for (int b = blockIdx.x; b < nblk; b += gridDim.x)
        s += part[(size_t)b * 256 + t];
    atomicAdd(&accum[t], s);
}

// ---------------------------------------------------------------- BN finalize+apply (f32 in/out, optional bf16 shadow)
template<bool SHADOW>
__global__ void bn_apply_f(float* __restrict__ a, short* __restrict__ shadow, long long total4,
                           const float* __restrict__ accum, const float* __restrict__ g,
                           const float* __restrict__ b, float invM) {
    __shared__ float scs[256];
    int t = threadIdx.x;
    if (t < 128) {
        float mean = accum[t] * invM;
        float var = accum[128 + t] * invM - mean * mean;
        float s = g[t] * rsqrtf(var + 1e-5f);
        scs[t] = s;
        scs[128 + t] = b[t] - mean * s;
    }
    __syncthreads();
    long long idx = (long long)blockIdx.x * 256 + t;
    long long stride = (long long)gridDim.x * 256;
    float4* a4 = (float4*)a;
    short4* s4p = (short4*)shadow;
    for (; idx < total4; idx += stride) {
        int c = (int)((idx & 31) * 4);
        float4 v = a4[idx];
        v.x = v.x * scs[c + 0] + scs[128 + c + 0];
        v.y = v.y * scs[c + 1] + scs[128 + c + 1];
        v.z = v.z * scs[c + 2] + scs[128 + c + 2];
        v.w = v.w * scs[c + 3] + scs[128 + c + 3];
        a4[idx] = v;
        if (SHADOW)
            s4p[idx] = make_short4(f2bf(v.x), f2bf(v.y), f2bf(v.z), f2bf(v.w));
    }
}

// ---------------------------------------------------------------- BN apply: f32 h -> bf16 shadow only
__global__ void bn_apply_shadow(const float* __restrict__ a, short* __restrict__ shadow,
                                long long total4, const float* __restrict__ accum,
                                const float* __restrict__ g, const float* __restrict__ b,
                                float invM) {
    __shared__ float scs[256];
    int t = threadIdx.x;
    if (t < 128) {
        float mean = accum[t] * invM;
        float var = accum[128 + t] * invM - mean * mean;
        float s = g[t] * rsqrtf(var + 1e-5f);
        scs[t] = s;
        scs[128 + t] = b[t] - mean * s;
    }
    __syncthreads();
    long long idx = (long long)blockIdx.x * 256 + t;
    long long stride = (long long)gridDim.x * 256;
    const float4* a4 = (const float4*)a;
    short4* s4p = (short4*)shadow;
    for (; idx < total4; idx += stride) {
        int c = (int)((idx & 31) * 4);
        float4 v = a4[idx];
        s4p[idx] = make_short4(f2bf(v.x * scs[c + 0] + scs[128 + c + 0]),
                               f2bf(v.y * scs[c + 1] + scs[128 + c + 1]),
                               f2bf(v.z * scs[c + 2] + scs[128 + c + 2]),
                               f2bf(v.w * scs[c + 3] + scs[128 + c + 3]));
    }
}

// ---------------------------------------------------------------- BN apply bf16 -> f32
__global__ void bn_apply_b2f(const short* __restrict__ inb, float* __restrict__ outp,
                             long long total4, const float* __restrict__ accum,
                             const float* __restrict__ g, const float* __restrict__ b, float invM) {
    __shared__ float scs[256];
    int t = threadIdx.x;
    if (t < 128) {
        float mean = accum[t] * invM;
        float var = accum[128 + t] * invM - mean * mean;
        float s = g[t] * rsqrtf(var + 1e-5f);
        scs[t] = s;
        scs[128 + t] = b[t] - mean * s;
    }
    __syncthreads();
    long long idx = (long long)blockIdx.x * 256 + t;
    long long stride = (long long)gridDim.x * 256;
    const short4* in4 = (const short4*)inb;
    float4* o4 = (float4*)outp;
    for (; idx < total4; idx += stride) {
        int c = (int)((idx & 31) * 4);
        short4 sv = in4[idx];
        float4 v;
        v.x = bf2f(sv.x) * scs[c + 0] + scs[128 + c + 0];
        v.y = bf2f(sv.y) * scs[c + 1] + scs[128 + c + 1];
        v.z = bf2f(sv.z) * scs[c + 2] + scs[128 + c + 2];
        v.w = bf2f(sv.w) * scs[c + 3] + scs[128 + c + 3];
        o4[idx] = v;
    }
}

// ---------------------------------------------------------------- w_att precompute
template<int H>
__global__ void watt_kernel(const float* __restrict__ lin, const float* __restrict__ att,
                            float* __restrict__ wx, float* __restrict__ we) {
    int t = threadIdx.x;            // H*128 threads
    int hh = t >> 7, d = t & 127;
    float sx = 0.f, se = 0.f;
    for (int j = 0; j < 128; ++j) {
        float l = lin[(size_t)d * (H * 128) + hh * 128 + j];
        sx += l * att[hh * 256 + j];
        se += l * att[hh * 256 + 128 + j];
    }
    wx[t] = sx;
    we[t] = se;
}

// ---------------------------------------------------------------- dual dots from bf16 shadow
template<int H>
__global__ void dots128_2(const short* __restrict__ hb, const float* __restrict__ wx,
                          const float* __restrict__ we, float* __restrict__ oax,
                          float* __restrict__ oaxe, int M) {
    int wv = threadIdx.x >> 6;
    int lane = threadIdx.x & 63;
    int row = blockIdx.x * 4 + wv;
    if (row >= M) return;
    const short* fr = hb + (size_t)row * 128;
    float f0 = bf2f(fr[lane]), f1 = bf2f(fr[lane + 64]);
    #pragma unroll
    for (int h = 0; h < H; ++h) {
        float va = f0 * wx[h * 128 + lane] + f1 * wx[h * 128 + lane + 64];
        float vb = f0 * we[h * 128 + lane] + f1 * we[h * 128 + lane + 64];
        #pragma unroll
        for (int s = 32; s > 0; s >>= 1) { va += __shfl_xor(va, s); vb += __shfl_xor(vb, s); }
        if (lane == 0) {
            oax[(size_t)row * H + h] = va;
            oaxe[(size_t)row * H + h] = vb;
        }
    }
}

// ---------------------------------------------------------------- FUSED: ae (edge sum of axe) + segment softmax
// phase-1 reduces all H heads in one 8-step LDS tree (was H sequential trees)
template<int H>
__global__ void edge_ae_softmax(const int* __restrict__ elist, const int* __restrict__ eoff,
                                const int* __restrict__ nidx, const float* __restrict__ ax,
                                const float* __restrict__ axe, float* __restrict__ alpha) {
    constexpr int SLOTS = 256 / H;
    __shared__ float red[256];
    __shared__ float red4[H][256];
    __shared__ float ae_sh[H];
    int e = blockIdx.x;
    int off = eoff[e], cnt = eoff[e + 1] - off;
    int t = threadIdx.x;
    int h = t % H, slot = t / H;

    {
        float acc[H];
        #pragma unroll
        for (int hh = 0; hh < H; ++hh) acc[hh] = 0.f;
        for (int p = t; p < cnt; p += 256) {
            int n = nidx[elist[off + p]];
            #pragma unroll
            for (int hh = 0; hh < H; ++hh) acc[hh] += axe[(size_t)n * H + hh];
        }
        #pragma unroll
        for (int hh = 0; hh < H; ++hh) red4[hh][t] = acc[hh];
        __syncthreads();
        for (int s = 128; s > 0; s >>= 1) {
            if (t < s) {
                #pragma unroll
                for (int hh = 0; hh < H; ++hh) red4[hh][t] += red4[hh][t + s];
            }
            __syncthreads();
        }
        if (t < H) ae_sh[t] = red4[t][0];
        __syncthreads();
    }
    float aeh = ae_sh[h];

    float lmax = -1e30f;
    for (int p = slot; p < cnt; p += SLOTS) {
        int k = elist[off + p];
        int n = nidx[k];
        float v = ax[(size_t)n * H + h] + aeh;
        v = v > 0.f ? v : 0.2f * v;
        alpha[(size_t)k * H + h] = v;
        lmax = fmaxf(lmax, v);
    }
    red[t] = lmax;
    __syncthreads();
    for (int s = SLOTS / 2; s > 0; s >>= 1) {
        if (slot < s) red[slot * H + h] = fmaxf(red[slot * H + h], red[(slot + s) * H + h]);
        __syncthreads();
    }
    float m = red[h];
    __syncthreads();
    float lsum = 0.f;
    for (int p = slot; p < cnt; p += SLOTS) {
        int k = elist[off + p];
        float ex = expf(alpha[(size_t)k * H + h] - m);
        alpha[(size_t)k * H + h] = ex;
        lsum += ex;
    }
    red[t] = lsum;
    __syncthreads();
    for (int s = SLOTS / 2; s > 0; s >>= 1) {
        if (slot < s) red[slot * H + h] += red[(slot + s) * H + h];
        __syncthreads();
    }
    float inv = 1.0f / (red[h] + 1e-16f);
    for (int p = slot; p < cnt; p += SLOTS) {
        int k = elist[off + p];
        alpha[(size_t)k * H + h] *= inv;
    }
}

// ---------------------------------------------------------------- FUSED: edge agg (bf16 gather) + lin projection
template<int H>
__global__ void edge_agg_lin(const int* __restrict__ elist, const int* __restrict__ eoff,
                             const int* __restrict__ nidx, const float* __restrict__ alpha,
                             const short* __restrict__ hb, const float* __restrict__ lin,
                             float* __restrict__ oute) {
    __shared__ int nIdx[128];
    __shared__ float aBuf[128 * H];
    __shared__ float ar[H * 128];
    int e = blockIdx.x;
    int off = eoff[e], cnt = eoff[e + 1] - off;
    int t = threadIdx.x;            // H*128 threads
    int hh = t >> 7, d = t & 127;
    float acc = 0.f;
    for (int base = 0; base < cnt; base += 128) {
        int c = cnt - base; if (c > 128) c = 128;
        if (t < c) {
            int k = elist[off + base + t];
            nIdx[t] = nidx[k];
            if (H == 4) {
                float4 a4 = *(const float4*)(alpha + (size_t)k * 4);
                aBuf[t * 4 + 0] = a4.x; aBuf[t * 4 + 1] = a4.y;
                aBuf[t * 4 + 2] = a4.z; aBuf[t * 4 + 3] = a4.w;
            } else {
                aBuf[t] = alpha[k];
            }
        }
        __syncthreads();
        #pragma unroll 4
        for (int j = 0; j < c; ++j)
            acc += aBuf[j * H + hh] * bf2f(hb[(size_t)nIdx[j] * 128 + d]);
        __syncthreads();
    }
    float binv = cnt > 0 ? 1.0f / (float)cnt : 0.0f;
    ar[t] = acc * binv;
    __syncthreads();
    float lacc = 0.f;
    #pragma unroll 4
    for (int dd = 0; dd < 128; ++dd)
        lacc += ar[hh * 128 + dd] * lin[(size_t)dd * (H * 128) + t];
    oute[(size_t)e * (H * 128) + t] = lacc;
}

// ---------------------------------------------------------------- node side: 3750 blocks x 4 sweeps
template<int H>
__global__ __launch_bounds__(256)
void node_aggregate2(const int* __restrict__ nlist, const int* __restrict__ noff,
                     const int* __restrict__ eidx, const float* __restrict__ alpha,
                     const float* __restrict__ oute, const float* __restrict__ bias,
                     float* __restrict__ hout, float* __restrict__ spart) {
    constexpr int MAXM = 32;
    __shared__ int   eLDS[2][MAXM];
    __shared__ float aLDS[2][MAXM][H];
    __shared__ float red[256];
    __shared__ int cshare[2];
    const int tid = threadIdx.x;
    const int sub = tid >> 7, d = tid & 127;
    const float bd = bias[d];
    float sts = 0.f, stq = 0.f;
    for (int sweep = 0; sweep < 4; ++sweep) {
        int n = sweep * 7500 + blockIdx.x * 2 + sub;
        int off = noff[n], cnt = noff[n + 1] - off;
        if (d == 0) cshare[sub] = cnt;
        __syncthreads();
        int cmax = max(cshare[0], cshare[1]);
        float acc[H];
        #pragma unroll
        for (int hh = 0; hh < H; ++hh) acc[hh] = 0.f;
        for (int base = 0; base < cmax; base += MAXM) {
            int chunkN = cnt - base;
            if (chunkN > MAXM) chunkN = MAXM;
            if (d < chunkN) {
                int k = nlist[off + base + d];
                eLDS[sub][d] = eidx[k];
                if (H == 4) {
                    float4 a4 = *(const float4*)(alpha + (size_t)k * 4);
                    aLDS[sub][d][0] = a4.x; aLDS[sub][d][1] = a4.y;
                    aLDS[sub][d][2] = a4.z; aLDS[sub][d][3] = a4.w;
                } else {
                    aLDS[sub][d][0] = alpha[k];
                }
            }
            __syncthreads();
            for (int j = 0; j < chunkN; ++j) {
                int e = eLDS[sub][j];
                #pragma unroll
                for (int hh = 0; hh < H; ++hh)
                    acc[hh] += aLDS[sub][j][hh] * oute[(size_t)e * (H * 128) + hh * 128 + d];
            }
            __syncthreads();
        }
        float s = 0.f;
        #pragma unroll
        for (int hh = 0; hh < H; ++hh) s += acc[hh];
        float dinv = cnt > 0 ? 1.0f / (float)cnt : 0.f;
        float nv = hout[(size_t)n * 128 + d] + s * (1.0f / H) * dinv + bd;
        hout[(size_t)n * 128 + d] = nv;
        sts += nv; stq += nv * nv;
        __syncthreads();
    }
    red[tid] = sts;
    __syncthreads();
    float tsum = (sub == 0) ? red[d] + red[128 + d] : 0.f;
    __syncthreads();
    red[tid] = stq;
    __syncthreads();
    if (sub == 0) {
        spart[(size_t)blockIdx.x * 256 + d] = tsum;
        spart[(size_t)blockIdx.x * 256 + 128 + d] = red[d] + red[128 + d];
    }
}

// ---------------------------------------------------------------- launch
extern "C" void kernel_launch(void* const* d_in, const int* in_sizes, int n_in,
                              void* d_out, int out_size, void* d_ws, size_t ws_size,
                              hipStream_t stream) {
    (void)in_sizes; (void)n_in; (void)out_size; (void)ws_size;
    const float* x        = (const float*)d_in[0];
    const int*   node_idx = (const int*)d_in[1];
    const int*   edge_idx = (const int*)d_in[2];
    const float* W1    = (const float*)d_in[4];
    const float* b1    = (const float*)d_in[5];
    const float* bn1_g = (const float*)d_in[6];
    const float* bn1_b = (const float*)d_in[7];
    const float* h1_lin  = (const float*)d_in[8];
    const float* h1_att  = (const float*)d_in[9];
    const float* h1_bias = (const float*)d_in[10];
    const float* bn2_g = (const float*)d_in[11];
    const float* bn2_b = (const float*)d_in[12];
    const float* h2_lin  = (const float*)d_in[13];
    const float* h2_att  = (const float*)d_in[14];
    const float* h2_bias = (const float*)d_in[15];
    const float* bn3_g = (const float*)d_in[16];
    const float* bn3_b = (const float*)d_in[17];
    const float* W2    = (const float*)d_in[18];
    const float* b2    = (const float*)d_in[19];
    const float* bn4_g = (const float*)d_in[20];
    const float* bn4_b = (const float*)d_in[21];
    float* out = (float*)d_out;

    char* ws = (char*)d_ws;
    size_t off = 0;
    auto alloc = [&](size_t bytes) -> void* {
        void* p = ws + off;
        off = (off + bytes + 255) & ~(size_t)255;
        return p;
    };
    float* h     = (float*)alloc((size_t)NN * 128 * 4);
    float* scratch = (float*)alloc((size_t)NN * 512 * 4);   // hp(bf16) early, outb late
    float* oute  = (float*)alloc((size_t)EE * 512 * 4);
    float* ax    = (float*)alloc((size_t)NN * 4 * 4);
    float* axe   = (float*)alloc((size_t)NN * 4 * 4);
    float* alpha = (float*)alloc((size_t)NNZC * 4 * 4);
    float* accum = (float*)alloc(256 * 4);
    float* spart = (float*)alloc((size_t)3752 * 256 * 4);
    float* wax   = (float*)alloc(512 * 4);
    float* wae   = (float*)alloc(512 * 4);
    short* hb    = (short*)alloc((size_t)NN * 128 * 2);    // bf16 shadow of h
    short* W1T   = (short*)alloc((size_t)128 * DIN * 2);
    short* W2T   = (short*)alloc((size_t)DIN * 128 * 2);
    int* ecnt  = (int*)alloc(EE * 4);
    int* eoff  = (int*)alloc((EE + 1) * 4);
    int* ecur  = (int*)alloc(EE * 4);
    int* elist = (int*)alloc(NNZC * 4);
    int* ncnt  = (int*)alloc(NN * 4);
    int* noff  = (int*)alloc((NN + 1) * 4);
    int* ncur  = (int*)alloc(NN * 4);
    int* nlist = (int*)alloc(NNZC * 4);

    short* hp   = (short*)scratch;     // split-K bf16 partials [4][NN][128]
    short* outb = (short*)scratch;     // pre-BN4 bf16 scratch (hp dead by then)

    hipMemsetAsync(ecnt, 0, EE * 4, stream);
    hipMemsetAsync(ncnt, 0, NN * 4, stream);
    hipMemsetAsync(ecur, 0, EE * 4, stream);
    hipMemsetAsync(ncur, 0, NN * 4, stream);

    count_kernel<<<(NNZC + 255) / 256, 256, 0, stream>>>(edge_idx, node_idx, ecnt, ncnt);
    transpose_to_bf16<<<dim3(4, 32), 256, 0, stream>>>(W1, W1T, DIN, 128);
    transpose_to_bf16<<<dim3(32, 4), 256, 0, stream>>>(W2, W2T, 128, DIN);
    scan_two<<<2, 1024, 0, stream>>>(ecnt, eoff, ncnt, noff);
    fill_lists<<<(NNZC + 255) / 256, 256, 0, stream>>>(edge_idx, node_idx, eoff, noff,
                                                       ecur, ncur, elist, nlist);

    const int MB64  = (NN + 63) / 64;     // 469
    const int MB128 = (NN + 127) / 128;   // 235

    // GEMM1 split-K=4 (bf16 partials) + combine (bias/leaky + BN1 stats)
    gemm1_splitk<<<4 * MB64, 256, 0, stream>>>(x, W1T, hp);
    hipMemsetAsync(accum, 0, 256 * 4, stream);
    combine_bn1<<<1024, 256, 0, stream>>>(hp, b1, h, spart);
    reduce_stats<<<32, 256, 0, stream>>>(spart, 1024, accum);
    bn_apply_f<true><<<1024, 256, 0, stream>>>(h, hb, (long long)NN * 128 / 4, accum,
                                               bn1_g, bn1_b, 1.0f / NN);

    // ---- hconv1 (heads=4), fused per-edge pipeline, bf16 gathers ----
    watt_kernel<4><<<1, 512, 0, stream>>>(h1_lin, h1_att, wax, wae);
    dots128_2<4><<<(NN + 3) / 4, 256, 0, stream>>>(hb, wax, wae, ax, axe, NN);
    edge_ae_softmax<4><<<EE, 256, 0, stream>>>(elist, eoff, node_idx, ax, axe, alpha);
    edge_agg_lin<4><<<EE, 512, 0, stream>>>(elist, eoff, node_idx, alpha, hb, h1_lin, oute);
    node_aggregate2<4><<<3750, 256, 0, stream>>>(nlist, noff, edge_idx, alpha, oute, h1_bias,
                                                 h, spart);

    // BN2 (stats fused in node_aggregate2)
    hipMemsetAsync(accum, 0, 256 * 4, stream);
    reduce_stats<<<32, 256, 0, stream>>>(spart, 3750, accum);
    bn_apply_f<true><<<1024, 256, 0, stream>>>(h, hb, (long long)NN * 128 / 4, accum,
                                               bn2_g, bn2_b, 1.0f / NN);

    // ---- hconv2 (heads=1), fused per-edge pipeline, bf16 gathers ----
    watt_kernel<1><<<1, 128, 0, stream>>>(h2_lin, h2_att, wax, wae);
    dots128_2<1><<<(NN + 3) / 4, 256, 0, stream>>>(hb, wax, wae, ax, axe, NN);
    edge_ae_softmax<1><<<EE, 256, 0, stream>>>(elist, eoff, node_idx, ax, axe, alpha);
    edge_agg_lin<1><<<EE, 128, 0, stream>>>(elist, eoff, node_idx, alpha, hb, h2_lin, oute);
    node_aggregate2<1><<<3750, 256, 0, stream>>>(nlist, noff, edge_idx, alpha, oute, h2_bias,
                                                 h, spart);

    // BN3: stats fused; shadow-only apply feeds W2
    hipMemsetAsync(accum, 0, 256 * 4, stream);
    reduce_stats<<<32, 256, 0, stream>>>(spart, 3750, accum);
    bn_apply_shadow<<<1024, 256, 0, stream>>>(h, hb, (long long)NN * 128 / 4, accum,
                                              bn3_g, bn3_b, 1.0f / NN);

    // out_pre = x + leaky(hb @ W2 + b2) -> bf16 scratch
    hipMemsetAsync(accum, 0, 256 * 4, stream);
    gemm_w2<<<8 * MB128, 512, 0, stream>>>(hb, W2T, b2, x, outb, spart);
    reduce_stats<<<32, 256, 0, stream>>>(spart, 8 * MB128, accum);

    // BN4: bf16 -> f32 out
    bn_apply_b2f<<<2048, 256, 0, stream>>>(outb, out, (long long)NN * DIN / 4, accum,
                                           bn4_g, bn4_b, 1.0f / (NN * PP));
}

// Round 24
// 509.170 us; speedup vs baseline: 1.0667x; 1.0667x over previous
//
#include <hip/hip_runtime.h>
#include <math.h>

#define NN 30000
#define PP 8
#define DM 128
#define EE 1000
#define NNZC 120000
#define DIN (PP*DM)   // 1024

typedef __attribute__((ext_vector_type(8))) short bf16x8;
typedef __attribute__((ext_vector_type(4))) float f32x4;

__device__ __forceinline__ short f2bf(float f) {
    union { float f; unsigned u; } v; v.f = f;
    unsigned r = v.u + 0x7fffu + ((v.u >> 16) & 1u);
    return (short)(r >> 16);
}
__device__ __forceinline__ float bf2f(short s) {
    union { unsigned u; float f; } v;
    v.u = ((unsigned)(unsigned short)s) << 16;
    return v.f;
}

// ---------------------------------------------------------------- CSR build
__global__ void count_kernel(const int* __restrict__ ei, const int* __restrict__ ni,
                             int* __restrict__ ecnt, int* __restrict__ ncnt) {
    int k = blockIdx.x * 256 + threadIdx.x;
    if (k >= NNZC) return;
    atomicAdd(&ecnt[ei[k]], 1);
    atomicAdd(&ncnt[ni[k]], 1);
}

__global__ __launch_bounds__(1024)
void scan_two(const int* __restrict__ ecnt, int* __restrict__ eoff,
              const int* __restrict__ ncnt, int* __restrict__ noff) {
    const int* cnt; int* off; int len;
    if (blockIdx.x == 0) { cnt = ecnt; off = eoff; len = EE; }
    else                 { cnt = ncnt; off = noff; len = NN; }
    __shared__ int wsum[16];
    __shared__ int carrysh;
    int t = threadIdx.x;
    int lane = t & 63, w = t >> 6;
    if (t == 0) carrysh = 0;
    __syncthreads();
    for (int base = 0; base < len; base += 1024) {
        int v = (base + t < len) ? cnt[base + t] : 0;
        int s = v;
        #pragma unroll
        for (int d = 1; d < 64; d <<= 1) {
            int u = __shfl_up(s, d);
            if (lane >= d) s += u;
        }
        if (lane == 63) wsum[w] = s;
        __syncthreads();
        if (t < 16) {
            int ws = wsum[t];
            #pragma unroll
            for (int d = 1; d < 16; d <<= 1) {
                int u = __shfl_up(ws, d);
                if (t >= d) ws += u;
            }
            wsum[t] = ws;
        }
        __syncthreads();
        int c = carrysh;
        int woff = (w > 0) ? wsum[w - 1] : 0;
        if (base + t < len) off[base + t] = c + woff + s - v;
        int total = wsum[15];
        __syncthreads();
        if (t == 0) carrysh = c + total;
    }
    __syncthreads();
    if (t == 0) off[len] = carrysh;
}

__global__ void fill_lists(const int* __restrict__ ei, const int* __restrict__ ni,
                           const int* __restrict__ eoff, const int* __restrict__ noff,
                           int* __restrict__ ecur, int* __restrict__ ncur,
                           int* __restrict__ elist, int* __restrict__ nlist) {
    int k = blockIdx.x * 256 + threadIdx.x;
    if (k >= NNZC) return;
    int e = ei[k];
    int p = atomicAdd(&ecur[e], 1);
    elist[eoff[e] + p] = k;
    int n = ni[k];
    int q = atomicAdd(&ncur[n], 1);
    nlist[noff[n] + q] = k;
}

// ---------------------------------------------------------------- weight transpose+convert
__global__ void transpose_to_bf16(const float* __restrict__ B, short* __restrict__ BT,
                                  int K, int N) {
    __shared__ float tile[32][33];
    int bn = blockIdx.x * 32, bk = blockIdx.y * 32;
    int tx = threadIdx.x & 31, ty = threadIdx.x >> 5;
    #pragma unroll
    for (int yy = ty; yy < 32; yy += 8) {
        int k = bk + yy, n = bn + tx;
        tile[yy][tx] = (k < K && n < N) ? B[(size_t)k * N + n] : 0.f;
    }
    __syncthreads();
    #pragma unroll
    for (int yy = ty; yy < 32; yy += 8) {
        int n = bn + yy, k = bk + tx;
        if (n < N && k < K) BT[(size_t)n * K + k] = f2bf(tile[tx][yy]);
    }
}

// ---------------------------------------------------------------- GEMM1 split-K=4 (bf16 partials)
__global__ __launch_bounds__(256)
void gemm1_splitk(const float* __restrict__ x, const short* __restrict__ W1T,
                  short* __restrict__ hp) {
    __shared__ short As[64 * 40];
    __shared__ short Bs[128 * 40];
    const int tid = threadIdx.x;
    const int lane = tid & 63, wid = tid >> 6;
    const int wm = wid >> 1, wn = wid & 1;
    const int panel = blockIdx.x >> 2, kq = blockIdx.x & 3;
    const int row0 = panel * 64;
    const int kbase = kq * 256;
    const int srow = tid >> 2, skq = tid & 3;

    f32x4 acc[2][4] = {};
    struct Stage { float4 fa[2]; bf16x8 b[2]; };
    Stage s0, s1;

    auto loadT = [&](int t, Stage& s) {
        int k0 = kbase + (t << 5);
        int gr = row0 + srow;
        float4 z = make_float4(0.f, 0.f, 0.f, 0.f);
        s.fa[0] = z; s.fa[1] = z;
        if (gr < NN) {
            const float4* p = (const float4*)(x + (size_t)gr * DIN + k0 + skq * 8);
            s.fa[0] = p[0]; s.fa[1] = p[1];
        }
        #pragma unroll
        for (int c = 0; c < 2; ++c)
            s.b[c] = *(const bf16x8*)(W1T + (size_t)(srow + 64 * c) * DIN + k0 + skq * 8);
    };
    auto writeT = [&](Stage& s) {
        bf16x8 t8;
        t8[0] = f2bf(s.fa[0].x); t8[1] = f2bf(s.fa[0].y);
        t8[2] = f2bf(s.fa[0].z); t8[3] = f2bf(s.fa[0].w);
        t8[4] = f2bf(s.fa[1].x); t8[5] = f2bf(s.fa[1].y);
        t8[6] = f2bf(s.fa[1].z); t8[7] = f2bf(s.fa[1].w);
        *(bf16x8*)&As[srow * 40 + skq * 8] = t8;
        #pragma unroll
        for (int c = 0; c < 2; ++c)
            *(bf16x8*)&Bs[(srow + 64 * c) * 40 + skq * 8] = s.b[c];
    };
    auto compute = [&]() {
        bf16x8 av[2], bv[4];
        #pragma unroll
        for (int i = 0; i < 2; ++i)
            av[i] = *(const bf16x8*)&As[(wm * 32 + i * 16 + (lane & 15)) * 40 + (lane >> 4) * 8];
        #pragma unroll
        for (int j = 0; j < 4; ++j)
            bv[j] = *(const bf16x8*)&Bs[(wn * 64 + j * 16 + (lane & 15)) * 40 + (lane >> 4) * 8];
        #pragma unroll
        for (int i = 0; i < 2; ++i)
            #pragma unroll
            for (int j = 0; j < 4; ++j)
                acc[i][j] = __builtin_amdgcn_mfma_f32_16x16x32_bf16(av[i], bv[j], acc[i][j], 0, 0, 0);
    };

    loadT(0, s0);
    for (int t = 0; t < 8; t += 2) {
        __syncthreads();
        loadT(t + 1, s1);
        writeT(s0);
        __syncthreads();
        compute();
        __syncthreads();
        if (t + 2 < 8) loadT(t + 2, s0);
        writeT(s1);
        __syncthreads();
        compute();
    }

    short* o = hp + (size_t)kq * NN * 128;
    #pragma unroll
    for (int i = 0; i < 2; ++i) {
        #pragma unroll
        for (int q = 0; q < 4; ++q) {
            int row = row0 + wm * 32 + i * 16 + (lane >> 4) * 4 + q;
            if (row < NN) {
                #pragma unroll
                for (int j = 0; j < 4; ++j) {
                    int col = wn * 64 + j * 16 + (lane & 15);
                    o[(size_t)row * 128 + col] = f2bf(acc[i][j][q]);
                }
            }
        }
    }
}

// ---------------------------------------------------------------- combine: h = leaky(sum hp(bf16) + b1), BN1 stats
__global__ void combine_bn1(const short* __restrict__ hp, const float* __restrict__ b1,
                            float* __restrict__ h, float* __restrict__ spart) {
    int t = threadIdx.x;
    const short4* p0 = (const short4*)hp;
    const short4* p1 = (const short4*)(hp + (size_t)NN * 128);
    const short4* p2 = (const short4*)(hp + (size_t)2 * NN * 128);
    const short4* p3 = (const short4*)(hp + (size_t)3 * NN * 128);
    float4* o = (float4*)h;
    int c = (t & 31) * 4;
    float4 bb = *(const float4*)(b1 + c);
    long long idx = (long long)blockIdx.x * 256 + t;
    long long stride = (long long)gridDim.x * 256;
    float s1[4] = {0.f,0.f,0.f,0.f}, s2[4] = {0.f,0.f,0.f,0.f};
    for (; idx < (long long)NN * 32; idx += stride) {
        short4 a = p0[idx], b = p1[idx], cc = p2[idx], dd = p3[idx];
        float v0 = bf2f(a.x) + bf2f(b.x) + bf2f(cc.x) + bf2f(dd.x) + bb.x;
        float v1 = bf2f(a.y) + bf2f(b.y) + bf2f(cc.y) + bf2f(dd.y) + bb.y;
        float v2 = bf2f(a.z) + bf2f(b.z) + bf2f(cc.z) + bf2f(dd.z) + bb.z;
        float v3 = bf2f(a.w) + bf2f(b.w) + bf2f(cc.w) + bf2f(dd.w) + bb.w;
        v0 = v0 > 0.f ? v0 : 0.2f * v0;
        v1 = v1 > 0.f ? v1 : 0.2f * v1;
        v2 = v2 > 0.f ? v2 : 0.2f * v2;
        v3 = v3 > 0.f ? v3 : 0.2f * v3;
        o[idx] = make_float4(v0, v1, v2, v3);
        s1[0] += v0; s2[0] += v0 * v0;
        s1[1] += v1; s2[1] += v1 * v1;
        s1[2] += v2; s2[2] += v2 * v2;
        s1[3] += v3; s2[3] += v3 * v3;
    }
    __shared__ float r1[256][4], r2[256][4];
    #pragma unroll
    for (int k = 0; k < 4; ++k) { r1[t][k] = s1[k]; r2[t][k] = s2[k]; }
    __syncthreads();
    if (t < 32) {
        #pragma unroll
        for (int k = 0; k < 4; ++k) {
            float a1 = 0.f, a2 = 0.f;
            #pragma unroll
            for (int u = 0; u < 8; ++u) { a1 += r1[t + u * 32][k]; a2 += r2[t + u * 32][k]; }
            spart[(size_t)blockIdx.x * 256 + t * 4 + k] = a1;
            spart[(size_t)blockIdx.x * 256 + 128 + t * 4 + k] = a2;
        }
    }
}

// ---------------------------------------------------------------- W2 GEMM: 128x128 tile, 8 waves (2x4)
__global__ __launch_bounds__(512)
void gemm_w2(const short* __restrict__ hb, const short* __restrict__ W2T,
             const float* __restrict__ bias, const float* __restrict__ srcf,
             short* __restrict__ outb, float* __restrict__ spart) {
    __shared__ short As[128 * 40];
    __shared__ short Bs[128 * 40];
    const int tid = threadIdx.x;
    const int lane = tid & 63, wid = tid >> 6;
    const int wm = wid >> 2, wn = wid & 3;        // 2 x 4 wave grid
    int row0, col0;
    {
        int w = blockIdx.x;
        int cpx = gridDim.x >> 3;
        int l = (w & 7) * cpx + (w >> 3);
        row0 = (l / 8) * 128;
        col0 = (l % 8) * 128;
    }
    const int sr = tid >> 2, kq = tid & 3;

    f32x4 acc[4][2] = {};
    struct Stage { bf16x8 a, b; };
    Stage s0, s1;

    auto loadT = [&](int t, Stage& s) {
        int k0 = t << 5;
        int gr = row0 + sr;
        s.a = bf16x8{0, 0, 0, 0, 0, 0, 0, 0};
        if (gr < NN) s.a = *(const bf16x8*)(hb + (size_t)gr * 128 + k0 + kq * 8);
        s.b = *(const bf16x8*)(W2T + (size_t)(col0 + sr) * 128 + k0 + kq * 8);
    };
    auto writeT = [&](Stage& s) {
        *(bf16x8*)&As[sr * 40 + kq * 8] = s.a;
        *(bf16x8*)&Bs[sr * 40 + kq * 8] = s.b;
    };
    auto compute = [&]() {
        bf16x8 av[4], bv[2];
        #pragma unroll
        for (int i = 0; i < 4; ++i)
            av[i] = *(const bf16x8*)&As[(wm * 64 + i * 16 + (lane & 15)) * 40 + (lane >> 4) * 8];
        #pragma unroll
        for (int j = 0; j < 2; ++j)
            bv[j] = *(const bf16x8*)&Bs[(wn * 32 + j * 16 + (lane & 15)) * 40 + (lane >> 4) * 8];
        #pragma unroll
        for (int i = 0; i < 4; ++i)
            #pragma unroll
            for (int j = 0; j < 2; ++j)
                acc[i][j] = __builtin_amdgcn_mfma_f32_16x16x32_bf16(av[i], bv[j], acc[i][j], 0, 0, 0);
    };

    loadT(0, s0);
    for (int t = 0; t < 4; t += 2) {
        __syncthreads();
        loadT(t + 1, s1);
        writeT(s0);
        __syncthreads();
        compute();
        __syncthreads();
        if (t + 2 < 4) loadT(t + 2, s0);
        writeT(s1);
        __syncthreads();
        compute();
    }

    float lsum[2] = {0.f, 0.f}, lsq[2] = {0.f, 0.f};
    #pragma unroll
    for (int i = 0; i < 4; ++i) {
        #pragma unroll
        for (int q = 0; q < 4; ++q) {
            int row = row0 + wm * 64 + i * 16 + (lane >> 4) * 4 + q;
            if (row < NN) {
                #pragma unroll
                for (int j = 0; j < 2; ++j) {
                    int col = col0 + wn * 32 + j * 16 + (lane & 15);
                    float val = acc[i][j][q];
                    val += bias[col];
                    val = val > 0.f ? val : 0.2f * val;
                    val += srcf[(size_t)row * DIN + col];
                    lsum[j] += val; lsq[j] += val * val;
                    outb[(size_t)row * DIN + col] = f2bf(val);
                }
            }
        }
    }
    __syncthreads();
    float* sred = (float*)As;
    if (tid < 256) sred[tid] = 0.f;
    __syncthreads();
    int chb = wn * 32 + (lane & 15);
    #pragma unroll
    for (int j = 0; j < 2; ++j) {
        atomicAdd(&sred[chb + j * 16], lsum[j]);
        atomicAdd(&sred[128 + chb + j * 16], lsq[j]);
    }
    __syncthreads();
    if (tid < 256) spart[(size_t)blockIdx.x * 256 + tid] = sred[tid];
}

// ---------------------------------------------------------------- fold per-block partials into accum[256]
__global__ void reduce_stats(const float* __restrict__ part, int nblk, float* __restrict__ accum) {
    int t = threadIdx.x;
    float s = 0.f;
    for (int b = blockIdx.x; b < nblk; b += gridDim.x)
        s += part[(size_t)b * 256 + t];
    atomicAdd(&accum[t], s);
}

// ---------------------------------------------------------------- BN finalize+apply (f32 in/out, optional bf16 shadow)
template<bool SHADOW>
__global__ void bn_apply_f(float* __restrict__ a, short* __restrict__ shadow, long long total4,
                           const float* __restrict__ accum, const float* __restrict__ g,
                           const float* __restrict__ b, float invM) {
    __shared__ float scs[256];
    int t = threadIdx.x;
    if (t < 128) {
        float mean = accum[t] * invM;
        float var = accum[128 + t] * invM - mean * mean;
        float s = g[t] * rsqrtf(var + 1e-5f);
        scs[t] = s;
        scs[128 + t] = b[t] - mean * s;
    }
    __syncthreads();
    long long idx = (long long)blockIdx.x * 256 + t;
    long long stride = (long long)gridDim.x * 256;
    float4* a4 = (float4*)a;
    short4* s4p = (short4*)shadow;
    for (; idx < total4; idx += stride) {
        int c = (int)((idx & 31) * 4);
        float4 v = a4[idx];
        v.x = v.x * scs[c + 0] + scs[128 + c + 0];
        v.y = v.y * scs[c + 1] + scs[128 + c + 1];
        v.z = v.z * scs[c + 2] + scs[128 + c + 2];
        v.w = v.w * scs[c + 3] + scs[128 + c + 3];
        a4[idx] = v;
        if (SHADOW)
            s4p[idx] = make_short4(f2bf(v.x), f2bf(v.y), f2bf(v.z), f2bf(v.w));
    }
}

// ---------------------------------------------------------------- BN apply: f32 h -> bf16 shadow only
__global__ void bn_apply_shadow(const float* __restrict__ a, short* __restrict__ shadow,
                                long long total4, const float* __restrict__ accum,
                                const float* __restrict__ g, const float* __restrict__ b,
                                float invM) {
    __shared__ float scs[256];
    int t = threadIdx.x;
    if (t < 128) {
        float mean = accum[t] * invM;
        float var = accum[128 + t] * invM - mean * mean;
        float s = g[t] * rsqrtf(var + 1e-5f);
        scs[t] = s;
        scs[128 + t] = b[t] - mean * s;
    }
    __syncthreads();
    long long idx = (long long)blockIdx.x * 256 + t;
    long long stride = (long long)gridDim.x * 256;
    const float4* a4 = (const float4*)a;
    short4* s4p = (short4*)shadow;
    for (; idx < total4; idx += stride) {
        int c = (int)((idx & 31) * 4);
        float4 v = a4[idx];
        s4p[idx] = make_short4(f2bf(v.x * scs[c + 0] + scs[128 + c + 0]),
                               f2bf(v.y * scs[c + 1] + scs[128 + c + 1]),
                               f2bf(v.z * scs[c + 2] + scs[128 + c + 2]),
                               f2bf(v.w * scs[c + 3] + scs[128 + c + 3]));
    }
}

// ---------------------------------------------------------------- BN apply bf16 -> f32
__global__ void bn_apply_b2f(const short* __restrict__ inb, float* __restrict__ outp,
                             long long total4, const float* __restrict__ accum,
                             const float* __restrict__ g, const float* __restrict__ b, float invM) {
    __shared__ float scs[256];
    int t = threadIdx.x;
    if (t < 128) {
        float mean = accum[t] * invM;
        float var = accum[128 + t] * invM - mean * mean;
        float s = g[t] * rsqrtf(var + 1e-5f);
        scs[t] = s;
        scs[128 + t] = b[t] - mean * s;
    }
    __syncthreads();
    long long idx = (long long)blockIdx.x * 256 + t;
    long long stride = (long long)gridDim.x * 256;
    const short4* in4 = (const short4*)inb;
    float4* o4 = (float4*)outp;
    for (; idx < total4; idx += stride) {
        int c = (int)((idx & 31) * 4);
        short4 sv = in4[idx];
        float4 v;
        v.x = bf2f(sv.x) * scs[c + 0] + scs[128 + c + 0];
        v.y = bf2f(sv.y) * scs[c + 1] + scs[128 + c + 1];
        v.z = bf2f(sv.z) * scs[c + 2] + scs[128 + c + 2];
        v.w = bf2f(sv.w) * scs[c + 3] + scs[128 + c + 3];
        o4[idx] = v;
    }
}

// ---------------------------------------------------------------- w_att precompute
template<int H>
__global__ void watt_kernel(const float* __restrict__ lin, const float* __restrict__ att,
                            float* __restrict__ wx, float* __restrict__ we) {
    int t = threadIdx.x;            // H*128 threads
    int hh = t >> 7, d = t & 127;
    float sx = 0.f, se = 0.f;
    for (int j = 0; j < 128; ++j) {
        float l = lin[(size_t)d * (H * 128) + hh * 128 + j];
        sx += l * att[hh * 256 + j];
        se += l * att[hh * 256 + 128 + j];
    }
    wx[t] = sx;
    we[t] = se;
}

// ---------------------------------------------------------------- dual dots from bf16 shadow
template<int H>
__global__ void dots128_2(const short* __restrict__ hb, const float* __restrict__ wx,
                          const float* __restrict__ we, float* __restrict__ oax,
                          float* __restrict__ oaxe, int M) {
    int wv = threadIdx.x >> 6;
    int lane = threadIdx.x & 63;
    int row = blockIdx.x * 4 + wv;
    if (row >= M) return;
    const short* fr = hb + (size_t)row * 128;
    float f0 = bf2f(fr[lane]), f1 = bf2f(fr[lane + 64]);
    #pragma unroll
    for (int h = 0; h < H; ++h) {
        float va = f0 * wx[h * 128 + lane] + f1 * wx[h * 128 + lane + 64];
        float vb = f0 * we[h * 128 + lane] + f1 * we[h * 128 + lane + 64];
        #pragma unroll
        for (int s = 32; s > 0; s >>= 1) { va += __shfl_xor(va, s); vb += __shfl_xor(vb, s); }
        if (lane == 0) {
            oax[(size_t)row * H + h] = va;
            oaxe[(size_t)row * H + h] = vb;
        }
    }
}

// ---------------------------------------------------------------- FUSED: ae (edge sum of axe) + segment softmax
template<int H>
__global__ void edge_ae_softmax(const int* __restrict__ elist, const int* __restrict__ eoff,
                                const int* __restrict__ nidx, const float* __restrict__ ax,
                                const float* __restrict__ axe, float* __restrict__ alpha) {
    constexpr int SLOTS = 256 / H;
    __shared__ float red[256];
    __shared__ float ae_sh[H];
    int e = blockIdx.x;
    int off = eoff[e], cnt = eoff[e + 1] - off;
    int t = threadIdx.x;
    int h = t % H, slot = t / H;

    {
        float acc[H];
        #pragma unroll
        for (int hh = 0; hh < H; ++hh) acc[hh] = 0.f;
        for (int p = t; p < cnt; p += 256) {
            int n = nidx[elist[off + p]];
            #pragma unroll
            for (int hh = 0; hh < H; ++hh) acc[hh] += axe[(size_t)n * H + hh];
        }
        #pragma unroll
        for (int hh = 0; hh < H; ++hh) {
            red[t] = acc[hh];
            __syncthreads();
            for (int s = 128; s > 0; s >>= 1) {
                if (t < s) red[t] += red[t + s];
                __syncthreads();
            }
            if (t == 0) ae_sh[hh] = red[0];
            __syncthreads();
        }
    }
    float aeh = ae_sh[h];

    float lmax = -1e30f;
    for (int p = slot; p < cnt; p += SLOTS) {
        int k = elist[off + p];
        int n = nidx[k];
        float v = ax[(size_t)n * H + h] + aeh;
        v = v > 0.f ? v : 0.2f * v;
        alpha[(size_t)k * H + h] = v;
        lmax = fmaxf(lmax, v);
    }
    red[t] = lmax;
    __syncthreads();
    for (int s = SLOTS / 2; s > 0; s >>= 1) {
        if (slot < s) red[slot * H + h] = fmaxf(red[slot * H + h], red[(slot + s) * H + h]);
        __syncthreads();
    }
    float m = red[h];
    __syncthreads();
    float lsum = 0.f;
    for (int p = slot; p < cnt; p += SLOTS) {
        int k = elist[off + p];
        float ex = expf(alpha[(size_t)k * H + h] - m);
        alpha[(size_t)k * H + h] = ex;
        lsum += ex;
    }
    red[t] = lsum;
    __syncthreads();
    for (int s = SLOTS / 2; s > 0; s >>= 1) {
        if (slot < s) red[slot * H + h] += red[(slot + s) * H + h];
        __syncthreads();
    }
    float inv = 1.0f / (red[h] + 1e-16f);
    for (int p = slot; p < cnt; p += SLOTS) {
        int k = elist[off + p];
        alpha[(size_t)k * H + h] *= inv;
    }
}

// ---------------------------------------------------------------- FUSED: edge agg (bf16 gather) + lin projection
template<int H>
__global__ void edge_agg_lin(const int* __restrict__ elist, const int* __restrict__ eoff,
                             const int* __restrict__ nidx, const float* __restrict__ alpha,
                             const short* __restrict__ hb, const float* __restrict__ lin,
                             float* __restrict__ oute) {
    __shared__ int nIdx[128];
    __shared__ float aBuf[128 * H];
    __shared__ float ar[H * 128];
    int e = blockIdx.x;
    int off = eoff[e], cnt = eoff[e + 1] - off;
    int t = threadIdx.x;            // H*128 threads
    int hh = t >> 7, d = t & 127;
    float acc = 0.f;
    for (int base = 0; base < cnt; base += 128) {
        int c = cnt - base; if (c > 128) c = 128;
        if (t < c) {
            int k = elist[off + base + t];
            nIdx[t] = nidx[k];
            if (H == 4) {
                float4 a4 = *(const float4*)(alpha + (size_t)k * 4);
                aBuf[t * 4 + 0] = a4.x; aBuf[t * 4 + 1] = a4.y;
                aBuf[t * 4 + 2] = a4.z; aBuf[t * 4 + 3] = a4.w;
            } else {
                aBuf[t] = alpha[k];
            }
        }
        __syncthreads();
        #pragma unroll 4
        for (int j = 0; j < c; ++j)
            acc += aBuf[j * H + hh] * bf2f(hb[(size_t)nIdx[j] * 128 + d]);
        __syncthreads();
    }
    float binv = cnt > 0 ? 1.0f / (float)cnt : 0.0f;
    ar[t] = acc * binv;
    __syncthreads();
    float lacc = 0.f;
    #pragma unroll 4
    for (int dd = 0; dd < 128; ++dd)
        lacc += ar[hh * 128 + dd] * lin[(size_t)dd * (H * 128) + t];
    oute[(size_t)e * (H * 128) + t] = lacc;
}

// ---------------------------------------------------------------- node side
template<int H>
__global__ __launch_bounds__(256)
void node_aggregate2(const int* __restrict__ nlist, const int* __restrict__ noff,
                     const int* __restrict__ eidx, const float* __restrict__ alpha,
                     const float* __restrict__ oute, const float* __restrict__ bias,
                     float* __restrict__ hout, float* __restrict__ spart) {
    constexpr int MAXM = 32;
    __shared__ int   eLDS[2][MAXM];
    __shared__ float aLDS[2][MAXM][H];
    __shared__ float red[256];
    __shared__ int cshare[2];
    const int tid = threadIdx.x;
    const int sub = tid >> 7, d = tid & 127;
    const float bd = bias[d];
    float sts = 0.f, stq = 0.f;
    for (int sweep = 0; sweep < 8; ++sweep) {
        int n = sweep * 3750 + blockIdx.x * 2 + sub;
        int off = noff[n], cnt = noff[n + 1] - off;
        if (d == 0) cshare[sub] = cnt;
        __syncthreads();
        int cmax = max(cshare[0], cshare[1]);
        float acc[H];
        #pragma unroll
        for (int hh = 0; hh < H; ++hh) acc[hh] = 0.f;
        for (int base = 0; base < cmax; base += MAXM) {
            int chunkN = cnt - base;
            if (chunkN > MAXM) chunkN = MAXM;
            if (d < chunkN) {
                int k = nlist[off + base + d];
                eLDS[sub][d] = eidx[k];
                if (H == 4) {
                    float4 a4 = *(const float4*)(alpha + (size_t)k * 4);
                    aLDS[sub][d][0] = a4.x; aLDS[sub][d][1] = a4.y;
                    aLDS[sub][d][2] = a4.z; aLDS[sub][d][3] = a4.w;
                } else {
                    aLDS[sub][d][0] = alpha[k];
                }
            }
            __syncthreads();
            for (int j = 0; j < chunkN; ++j) {
                int e = eLDS[sub][j];
                #pragma unroll
                for (int hh = 0; hh < H; ++hh)
                    acc[hh] += aLDS[sub][j][hh] * oute[(size_t)e * (H * 128) + hh * 128 + d];
            }
            __syncthreads();
        }
        float s = 0.f;
        #pragma unroll
        for (int hh = 0; hh < H; ++hh) s += acc[hh];
        float dinv = cnt > 0 ? 1.0f / (float)cnt : 0.f;
        float nv = hout[(size_t)n * 128 + d] + s * (1.0f / H) * dinv + bd;
        hout[(size_t)n * 128 + d] = nv;
        sts += nv; stq += nv * nv;
        __syncthreads();
    }
    red[tid] = sts;
    __syncthreads();
    float tsum = (sub == 0) ? red[d] + red[128 + d] : 0.f;
    __syncthreads();
    red[tid] = stq;
    __syncthreads();
    if (sub == 0) {
        spart[(size_t)blockIdx.x * 256 + d] = tsum;
        spart[(size_t)blockIdx.x * 256 + 128 + d] = red[d] + red[128 + d];
    }
}

// ---------------------------------------------------------------- launch
extern "C" void kernel_launch(void* const* d_in, const int* in_sizes, int n_in,
                              void* d_out, int out_size, void* d_ws, size_t ws_size,
                              hipStream_t stream) {
    (void)in_sizes; (void)n_in; (void)out_size; (void)ws_size;
    const float* x        = (const float*)d_in[0];
    const int*   node_idx = (const int*)d_in[1];
    const int*   edge_idx = (const int*)d_in[2];
    const float* W1    = (const float*)d_in[4];
    const float* b1    = (const float*)d_in[5];
    const float* bn1_g = (const float*)d_in[6];
    const float* bn1_b = (const float*)d_in[7];
    const float* h1_lin  = (const float*)d_in[8];
    const float* h1_att  = (const float*)d_in[9];
    const float* h1_bias = (const float*)d_in[10];
    const float* bn2_g = (const float*)d_in[11];
    const float* bn2_b = (const float*)d_in[12];
    const float* h2_lin  = (const float*)d_in[13];
    const float* h2_att  = (const float*)d_in[14];
    const float* h2_bias = (const float*)d_in[15];
    const float* bn3_g = (const float*)d_in[16];
    const float* bn3_b = (const float*)d_in[17];
    const float* W2    = (const float*)d_in[18];
    const float* b2    = (const float*)d_in[19];
    const float* bn4_g = (const float*)d_in[20];
    const float* bn4_b = (const float*)d_in[21];
    float* out = (float*)d_out;

    char* ws = (char*)d_ws;
    size_t off = 0;
    auto alloc = [&](size_t bytes) -> void* {
        void* p = ws + off;
        off = (off + bytes + 255) & ~(size_t)255;
        return p;
    };
    float* h     = (float*)alloc((size_t)NN * 128 * 4);
    float* scratch = (float*)alloc((size_t)NN * 512 * 4);   // hp(bf16) early, outb late
    float* oute  = (float*)alloc((size_t)EE * 512 * 4);
    float* ax    = (float*)alloc((size_t)NN * 4 * 4);
    float* axe   = (float*)alloc((size_t)NN * 4 * 4);
    float* alpha = (float*)alloc((size_t)NNZC * 4 * 4);
    float* accum = (float*)alloc(256 * 4);
    float* spart = (float*)alloc((size_t)1880 * 256 * 4);
    float* wax   = (float*)alloc(512 * 4);
    float* wae   = (float*)alloc(512 * 4);
    short* hb    = (short*)alloc((size_t)NN * 128 * 2);    // bf16 shadow of h
    short* W1T   = (short*)alloc((size_t)128 * DIN * 2);
    short* W2T   = (short*)alloc((size_t)DIN * 128 * 2);
    int* ecnt  = (int*)alloc(EE * 4);
    int* eoff  = (int*)alloc((EE + 1) * 4);
    int* ecur  = (int*)alloc(EE * 4);
    int* elist = (int*)alloc(NNZC * 4);
    int* ncnt  = (int*)alloc(NN * 4);
    int* noff  = (int*)alloc((NN + 1) * 4);
    int* ncur  = (int*)alloc(NN * 4);
    int* nlist = (int*)alloc(NNZC * 4);

    short* hp   = (short*)scratch;     // split-K bf16 partials [4][NN][128]
    short* outb = (short*)scratch;     // pre-BN4 bf16 scratch (hp dead by then)

    hipMemsetAsync(ecnt, 0, EE * 4, stream);
    hipMemsetAsync(ncnt, 0, NN * 4, stream);
    hipMemsetAsync(ecur, 0, EE * 4, stream);
    hipMemsetAsync(ncur, 0, NN * 4, stream);

    count_kernel<<<(NNZC + 255) / 256, 256, 0, stream>>>(edge_idx, node_idx, ecnt, ncnt);
    transpose_to_bf16<<<dim3(4, 32), 256, 0, stream>>>(W1, W1T, DIN, 128);
    transpose_to_bf16<<<dim3(32, 4), 256, 0, stream>>>(W2, W2T, 128, DIN);
    scan_two<<<2, 1024, 0, stream>>>(ecnt, eoff, ncnt, noff);
    fill_lists<<<(NNZC + 255) / 256, 256, 0, stream>>>(edge_idx, node_idx, eoff, noff,
                                                       ecur, ncur, elist, nlist);

    const int MB64  = (NN + 63) / 64;     // 469
    const int MB128 = (NN + 127) / 128;   // 235

    // GEMM1 split-K=4 (bf16 partials) + combine (bias/leaky + BN1 stats)
    gemm1_splitk<<<4 * MB64, 256, 0, stream>>>(x, W1T, hp);
    hipMemsetAsync(accum, 0, 256 * 4, stream);
    combine_bn1<<<1024, 256, 0, stream>>>(hp, b1, h, spart);
    reduce_stats<<<32, 256, 0, stream>>>(spart, 1024, accum);
    bn_apply_f<true><<<1024, 256, 0, stream>>>(h, hb, (long long)NN * 128 / 4, accum,
                                               bn1_g, bn1_b, 1.0f / NN);

    // ---- hconv1 (heads=4), fused per-edge pipeline, bf16 gathers ----
    watt_kernel<4><<<1, 512, 0, stream>>>(h1_lin, h1_att, wax, wae);
    dots128_2<4><<<(NN + 3) / 4, 256, 0, stream>>>(hb, wax, wae, ax, axe, NN);
    edge_ae_softmax<4><<<EE, 256, 0, stream>>>(elist, eoff, node_idx, ax, axe, alpha);
    edge_agg_lin<4><<<EE, 512, 0, stream>>>(elist, eoff, node_idx, alpha, hb, h1_lin, oute);
    node_aggregate2<4><<<1875, 256, 0, stream>>>(nlist, noff, edge_idx, alpha, oute, h1_bias,
                                                 h, spart);

    // BN2 (stats fused in node_aggregate2)
    hipMemsetAsync(accum, 0, 256 * 4, stream);
    reduce_stats<<<32, 256, 0, stream>>>(spart, 1875, accum);
    bn_apply_f<true><<<1024, 256, 0, stream>>>(h, hb, (long long)NN * 128 / 4, accum,
                                               bn2_g, bn2_b, 1.0f / NN);

    // ---- hconv2 (heads=1), fused per-edge pipeline, bf16 gathers ----
    watt_kernel<1><<<1, 128, 0, stream>>>(h2_lin, h2_att, wax, wae);
    dots128_2<1><<<(NN + 3) / 4, 256, 0, stream>>>(hb, wax, wae, ax, axe, NN);
    edge_ae_softmax<1><<<EE, 256, 0, stream>>>(elist, eoff, node_idx, ax, axe, alpha);
    edge_agg_lin<1><<<EE, 128, 0, stream>>>(elist, eoff, node_idx, alpha, hb, h2_lin, oute);
    node_aggregate2<1><<<1875, 256, 0, stream>>>(nlist, noff, edge_idx, alpha, oute, h2_bias,
                                                 h, spart);

    // BN3: stats fused; shadow-only apply feeds W2
    hipMemsetAsync(accum, 0, 256 * 4, stream);
    reduce_stats<<<32, 256, 0, stream>>>(spart, 1875, accum);
    bn_apply_shadow<<<1024, 256, 0, stream>>>(h, hb, (long long)NN * 128 / 4, accum,
                                              bn3_g, bn3_b, 1.0f / NN);

    // out_pre = x + leaky(hb @ W2 + b2) -> bf16 scratch
    hipMemsetAsync(accum, 0, 256 * 4, stream);
    gemm_w2<<<8 * MB128, 512, 0, stream>>>(hb, W2T, b2, x, outb, spart);
    reduce_stats<<<32, 256, 0, stream>>>(spart, 8 * MB128, accum);

    // BN4: bf16 -> f32 out
    bn_apply_b2f<<<2048, 256, 0, stream>>>(outb, out, (long long)NN * DIN / 4, accum,
                                           bn4_g, bn4_b, 1.0f / (NN * PP));
}